// Round 26
// baseline (675.279 us; speedup 1.0000x reference)
//
#include <hip/hip_runtime.h>

#define Hh 256
#define Ww 256
#define NB 4
#define NM 64
#define KP 7
#define HW (Hh*Ww)
#define NX (NB*HW)                 // 262144 xhat pixels
#define NZQ ((size_t)NB*NM*HW)     // 16777216 z pixels
#define PT 32                      // px tile (32x32)
#define TW2 38                     // PT + 6 halo
#define LDS2 40                    // padded stride
#define NST 6                      // staging slots per thread
#define NTAP (3*NM*49)             // 9408 weight taps per array
#define NSPL 4                     // channel splits (16 ch per block)

typedef unsigned short u16;
typedef unsigned int u32;

__device__ __forceinline__ float bf2f(u16 u) {
  union { u32 i; float f; } c; c.i = ((u32)u) << 16; return c.f;
}
__device__ __forceinline__ u16 f2bf(float f) {
  union { float f; u32 i; } c; c.f = f;
  return (u16)((c.i + 0x7FFFu + ((c.i >> 16) & 1u)) >> 16);   // RNE
}
__device__ __forceinline__ ushort2 packbf(float x, float y) {
  return make_ushort2(f2bf(x), f2bf(y));
}

// ---- f16 pair helpers (packed complex value in one dword: low=re, high=im) ----
__device__ __forceinline__ u32 packh(float x, float y) {
  union { u32 u; _Float16 h[2]; } c;
  c.h[0] = (_Float16)x; c.h[1] = (_Float16)y;
  return c.u;
}
__device__ __forceinline__ float2 unpackh(u32 v) {
  union { u32 u; _Float16 h[2]; } c; c.u = v;
  return make_float2((float)c.h[0], (float)c.h[1]);
}
__device__ __forceinline__ u16 h2bf(u16 hraw) {
  union { u16 u; _Float16 h; } c; c.u = hraw;
  return f2bf((float)c.h);
}

#if __has_builtin(__builtin_amdgcn_fdot2)
typedef _Float16 hf2 __attribute__((ext_vector_type(2)));
__device__ __forceinline__ void cmac2(float& ar, float& ai, u32 v, u32 wre, u32 wim) {
  union { u32 u; hf2 h; } a, b, c;
  a.u = v; b.u = wre; c.u = wim;
  ar = __builtin_amdgcn_fdot2(a.h, b.h, ar, false);
  ai = __builtin_amdgcn_fdot2(a.h, c.h, ai, false);
}
#else
__device__ __forceinline__ void cmac2(float& ar, float& ai, u32 v, u32 wre, u32 wim) {
  float2 a = unpackh(v), b = unpackh(wre), c = unpackh(wim);
  ar = fmaf(a.x, b.x, ar); ar = fmaf(a.y, b.y, ar);
  ai = fmaf(a.x, c.x, ai); ai = fmaf(a.y, c.y, ai);
}
#endif

// soft-threshold factor: max(1 - t*rsqrt(s), 0), s = re^2+im^2.
// s=0 -> rsqrt=inf -> (t>0: -inf, t=0: NaN) -> fmaxf returns 0. Correct.
__device__ __forceinline__ float stfac(float s, float t) {
  return fmaxf(1.f - t*rsqrtf(s), 0.f);
}

// ---------------- weight prep: pack (wr,-wi),(wi,wr) as f16 pairs ----------------
__global__ __launch_bounds__(256) void wprep_kernel(
    const float* __restrict__ Awre, const float* __restrict__ Awim,
    const float* __restrict__ Bwre, const float* __restrict__ Bwim,
    uint2* __restrict__ wA, uint2* __restrict__ wB) {
  int i = blockIdx.x*256 + threadIdx.x;
  if (i < NTAP) {
    float wr = Awre[i], wi = Awim[i];
    wA[i] = make_uint2(packh(wr, -wi), packh(wi, wr));
    wr = Bwre[i]; wi = Bwim[i];
    wB[i] = make_uint2(packh(wr, -wi), packh(wi, wr));
  }
}

// ---------------- mean over (C,H,W) per batch, complex ----------------
__global__ __launch_bounds__(256) void mean_stage1(
    const float* __restrict__ yre, const float* __restrict__ yim,
    float2* __restrict__ part) {
  int blk = blockIdx.x;           // 256 blocks: 64 per batch
  int b = blk >> 6, chunk = blk & 63;
  int tid = threadIdx.x;
  int base = b*HW + chunk*1024;
  float sr = 0.f, si = 0.f;
  #pragma unroll
  for (int j = 0; j < 4; ++j) {
    sr += yre[base + tid + j*256];
    si += yim[base + tid + j*256];
  }
  #pragma unroll
  for (int off = 32; off > 0; off >>= 1) {
    sr += __shfl_down(sr, off);
    si += __shfl_down(si, off);
  }
  __shared__ float2 red[4];
  if ((tid & 63) == 0) red[tid >> 6] = make_float2(sr, si);
  __syncthreads();
  if (tid == 0) {
    float2 a = red[0], b2 = red[1], c = red[2], d = red[3];
    part[blk] = make_float2(a.x + b2.x + c.x + d.x, a.y + b2.y + c.y + d.y);
  }
}

__global__ __launch_bounds__(256) void mean_stage2(
    const float2* __restrict__ part, float2* __restrict__ mean) {
  int tid = threadIdx.x;
  int b = tid >> 6, lane = tid & 63;
  float2 v = part[b*64 + lane];
  float sr = v.x, si = v.y;
  #pragma unroll
  for (int off = 32; off > 0; off >>= 1) {
    sr += __shfl_down(sr, off);
    si += __shfl_down(si, off);
  }
  if (lane == 0) mean[b] = make_float2(sr / (float)HW, si / (float)HW);
}

// ---------------- z0 = ST(conv(yp, A0), t[0,0]) — 16ch/block, 8ch/group ----------------
__global__ __launch_bounds__(256) void conv_first_kernel(
    const float* __restrict__ yre, const float* __restrict__ yim,
    const float2* __restrict__ mean,
    const uint2* __restrict__ wA,
    const float* __restrict__ t, u32* __restrict__ z) {
  int tid = threadIdx.x;
  int blk = blockIdx.x;                 // 1024 = ms + 4*(txi + 8*(tyi + 8*b))
  int ms  = blk & 3;
  int txi = (blk >> 2) & 7, tyi = (blk >> 5) & 7, b = (blk >> 8) & 3;
  int ty0 = tyi*PT, tx0 = txi*PT;
  int thy = tid >> 4, thx = tid & 15;

  __shared__ u32 tile[TW2][LDS2];
  float2 mb = mean[b];
  const float* re = yre + b*HW;
  const float* im = yim + b*HW;
  for (int i = tid; i < TW2*TW2; i += 256) {
    int rr = i / TW2, cc = i - rr*TW2;
    int gy = ty0 - 3 + rr, gx = tx0 - 3 + cc;
    u32 v = 0;
    if ((unsigned)gy < Hh && (unsigned)gx < Ww) {
      int o = gy*Ww + gx;
      v = packh(re[o] - mb.x, im[o] - mb.y);
    }
    tile[rr][cc] = v;
  }
  __syncthreads();

  u32* zb = z + ((size_t)b*NM << 16);
  int m0 = ms*16;
  #pragma unroll 1
  for (int mm = 0; mm < 16; mm += 8) {
    int m = m0 + mm;
    const uint2* w0p = wA + m*49;       // k = 0
    float ar[8][4], ai[8][4];
    #pragma unroll
    for (int c = 0; c < 8; ++c)
      #pragma unroll
      for (int p = 0; p < 4; ++p) { ar[c][p] = 0.f; ai[c][p] = 0.f; }
    #pragma unroll
    for (int ky = 0; ky < KP; ++ky) {
      #pragma unroll
      for (int kx = 0; kx < KP; ++kx) {
        int wo = ky*KP + kx;
        uint2 w[8];
        #pragma unroll
        for (int c = 0; c < 8; ++c) w[c] = w0p[c*49 + wo];
        #pragma unroll
        for (int dy = 0; dy < 2; ++dy) {
          #pragma unroll
          for (int dx = 0; dx < 2; ++dx) {
            u32 v = tile[thy + dy*16 + ky][thx + dx*16 + kx];
            int p = dy*2 + dx;
            #pragma unroll
            for (int c = 0; c < 8; ++c)
              cmac2(ar[c][p], ai[c][p], v, w[c].x, w[c].y);
          }
        }
      }
    }
    #pragma unroll
    for (int c = 0; c < 8; ++c) {
      float tc = t[m + c];              // t[0,0,m+c]
      #pragma unroll
      for (int dy = 0; dy < 2; ++dy) {
        #pragma unroll
        for (int dx = 0; dx < 2; ++dx) {
          int p = dy*2 + dx;
          size_t o = (size_t)(ty0 + thy + dy*16)*Ww + tx0 + thx + dx*16;
          float s = ar[c][p]*ar[c][p] + ai[c][p]*ai[c][p];
          float f = stfac(s, tc);
          zb[((size_t)(m + c) << 16) + o] = packh(ar[c][p]*f, ai[c][p]*f);
        }
      }
    }
  }
}

// ---------------- partial convT over 16 ch (4ch packed uint4, single-buffer) ----------------
__global__ __launch_bounds__(256) void convT_part_kernel(
    const u32* __restrict__ z,
    const uint2* __restrict__ wB,
    int k, float2* __restrict__ rpart) {
  int tid = threadIdx.x;
  int blk = blockIdx.x;                 // 1024 = s + 4*(txi + 8*(tyi + 8*b))
  int s   = blk & 3;
  int txi = (blk >> 2) & 7, tyi = (blk >> 5) & 7, b = (blk >> 8) & 3;
  int ty0 = tyi*PT, tx0 = txi*PT;
  int thy = tid >> 4, thx = tid & 15;

  __shared__ uint4 tile[TW2][LDS2];     // 4 consecutive channels per element (24320 B)

  int srr[NST], scc[NST], soff[NST];
  bool sok[NST], sin[NST];
  #pragma unroll
  for (int j = 0; j < NST; ++j) {
    int i = tid + j*256;
    sin[j] = i < TW2*TW2;
    int rr = sin[j] ? i / TW2 : 0;
    int cc = sin[j] ? i - rr*TW2 : 0;
    int gy = ty0 - 3 + rr, gx = tx0 - 3 + cc;
    sok[j] = sin[j] && (unsigned)gy < Hh && (unsigned)gx < Ww;
    srr[j] = rr; scc[j] = cc;
    soff[j] = sok[j] ? gy*Ww + gx : 0;
  }

  const u32* zb = z + ((size_t)b*NM << 16);
  int m0 = s*16;

  float ar[4] = {0.f,0.f,0.f,0.f}, ai[4] = {0.f,0.f,0.f,0.f};
  #pragma unroll 1
  for (int q = 0; q < 4; ++q) {         // 4 channel quads
    int m = m0 + 4*q;
    if (q) __syncthreads();             // protect previous iteration's reads
    {
      const u32* z0 = zb + ((size_t)m << 16);
      const u32* z1 = zb + ((size_t)(m + 1) << 16);
      const u32* z2 = zb + ((size_t)(m + 2) << 16);
      const u32* z3 = zb + ((size_t)(m + 3) << 16);
      #pragma unroll
      for (int j = 0; j < NST; ++j)
        if (sin[j]) tile[srr[j]][scc[j]] = make_uint4(
          sok[j] ? z0[soff[j]] : 0u, sok[j] ? z1[soff[j]] : 0u,
          sok[j] ? z2[soff[j]] : 0u, sok[j] ? z3[soff[j]] : 0u);
    }
    __syncthreads();

    const uint2* w0p = wB + (k*NM + m)*49;
    #pragma unroll
    for (int ky = 0; ky < KP; ++ky) {
      #pragma unroll
      for (int kx = 0; kx < KP; ++kx) {
        int wo = ky*KP + kx;
        uint2 wa = w0p[wo], wb = w0p[49 + wo], wc = w0p[98 + wo], wd = w0p[147 + wo];
        #pragma unroll
        for (int dy = 0; dy < 2; ++dy) {
          #pragma unroll
          for (int dx = 0; dx < 2; ++dx) {
            uint4 v = tile[thy + dy*16 + 6 - ky][thx + dx*16 + 6 - kx];
            int p = dy*2 + dx;
            cmac2(ar[p], ai[p], v.x, wa.x, wa.y);
            cmac2(ar[p], ai[p], v.y, wb.x, wb.y);
            cmac2(ar[p], ai[p], v.z, wc.x, wc.y);
            cmac2(ar[p], ai[p], v.w, wd.x, wd.y);
          }
        }
      }
    }
  }

  float2* rp = rpart + (size_t)s*NB*HW + (size_t)b*HW;
  #pragma unroll
  for (int dy = 0; dy < 2; ++dy) {
    #pragma unroll
    for (int dx = 0; dx < 2; ++dx) {
      int p = dy*2 + dx;
      int o = (ty0 + thy + dy*16)*Ww + tx0 + thx + dx*16;
      rp[o] = make_float2(ar[p], ai[p]);
    }
  }
}

// ---------------- rfold: rq = packh(Σ4 rpart − (y − mean)) ----------------
__global__ __launch_bounds__(256) void rfold_kernel(
    const float2* __restrict__ rpart,
    const float* __restrict__ yre, const float* __restrict__ yim,
    const float2* __restrict__ mean, u32* __restrict__ rq) {
  int p = blockIdx.x*256 + threadIdx.x;   // 0..NX (p = b*HW + px)
  int b = p >> 16;
  float2 mb = mean[b];
  float2 p0 = rpart[p];
  float2 p1 = rpart[(size_t)NB*HW + p];
  float2 p2 = rpart[(size_t)2*NB*HW + p];
  float2 p3 = rpart[(size_t)3*NB*HW + p];
  rq[p] = packh(p0.x + p1.x + p2.x + p3.x - (yre[p] - mb.x),
                p0.y + p1.y + p2.y + p3.y - (yim[p] - mb.y));
}

// ---------------- z = ST(z - conv(rq, A[k]), t[k,0]) — 16ch/block, 8ch/group ----------------
__global__ __launch_bounds__(256) void conv_update_kernel(
    const u32* __restrict__ rq,
    const uint2* __restrict__ wA,
    const float* __restrict__ t, int k, u32* __restrict__ z) {
  int tid = threadIdx.x;
  int blk = blockIdx.x;                 // 1024 = ms + 4*(txi + 8*(tyi + 8*b))
  int ms  = blk & 3;
  int txi = (blk >> 2) & 7, tyi = (blk >> 5) & 7, b = (blk >> 8) & 3;
  int ty0 = tyi*PT, tx0 = txi*PT;
  int thy = tid >> 4, thx = tid & 15;

  __shared__ u32 tile[TW2][LDS2];
  const u32* rb = rq + b*HW;
  for (int i = tid; i < TW2*TW2; i += 256) {
    int rr = i / TW2, cc = i - rr*TW2;
    int gy = ty0 - 3 + rr, gx = tx0 - 3 + cc;
    u32 v = 0;
    if ((unsigned)gy < Hh && (unsigned)gx < Ww) v = rb[gy*Ww + gx];
    tile[rr][cc] = v;
  }
  __syncthreads();

  const float* tw = t + k*2*NM;         // t[k,0,:]
  u32* zb = z + ((size_t)b*NM << 16);
  int m0 = ms*16;
  #pragma unroll 1
  for (int mm = 0; mm < 16; mm += 8) {
    int m = m0 + mm;
    const uint2* w0p = wA + (k*NM + m)*49;
    float ar[8][4], ai[8][4];
    #pragma unroll
    for (int c = 0; c < 8; ++c)
      #pragma unroll
      for (int p = 0; p < 4; ++p) { ar[c][p] = 0.f; ai[c][p] = 0.f; }
    #pragma unroll
    for (int ky = 0; ky < KP; ++ky) {
      #pragma unroll
      for (int kx = 0; kx < KP; ++kx) {
        int wo = ky*KP + kx;
        uint2 w[8];
        #pragma unroll
        for (int c = 0; c < 8; ++c) w[c] = w0p[c*49 + wo];
        #pragma unroll
        for (int dy = 0; dy < 2; ++dy) {
          #pragma unroll
          for (int dx = 0; dx < 2; ++dx) {
            u32 v = tile[thy + dy*16 + ky][thx + dx*16 + kx];
            int p = dy*2 + dx;
            #pragma unroll
            for (int c = 0; c < 8; ++c)
              cmac2(ar[c][p], ai[c][p], v, w[c].x, w[c].y);
          }
        }
      }
    }
    #pragma unroll
    for (int c = 0; c < 8; ++c) {
      float tc = tw[m + c];
      #pragma unroll
      for (int dy = 0; dy < 2; ++dy) {
        #pragma unroll
        for (int dx = 0; dx < 2; ++dx) {
          int p = dy*2 + dx;
          size_t o = (size_t)(ty0 + thy + dy*16)*Ww + tx0 + thx + dx*16;
          size_t q0 = ((size_t)(m + c) << 16) + o;
          float2 z0 = unpackh(zb[q0]);
          float zr0 = z0.x - ar[c][p], zi0 = z0.y - ai[c][p];
          float s = zr0*zr0 + zi0*zi0;
          float f = stfac(s, tc);
          zb[q0] = packh(zr0*f, zi0*f);
        }
      }
    }
  }
}

// ---------------- xhat partial reduce: xws = bf16(Σx + mean) ----------------
__global__ __launch_bounds__(256) void xreduce_kernel(
    const float2* __restrict__ xpart,
    const float2* __restrict__ mean, ushort2* __restrict__ xws) {
  int p = blockIdx.x*256 + threadIdx.x;   // 0..NX
  int b = p >> 16;
  float2 mb = mean[b];
  float2 a0 = xpart[p];
  float2 a1 = xpart[(size_t)NB*HW + p];
  float2 a2 = xpart[(size_t)2*NB*HW + p];
  float2 a3 = xpart[(size_t)3*NB*HW + p];
  xws[p] = packbf(a0.x + a1.x + a2.x + a3.x + mb.x,
                  a0.y + a1.y + a2.y + a3.y + mb.y);
}

// ---------------- emit: shifted (+1 element) copy into d_out; z f16->bf16 ----------------
__global__ __launch_bounds__(256) void emit_kernel(
    const ushort2* __restrict__ xws, const u32* __restrict__ zws,
    u16* __restrict__ out16) {
  size_t idx = (size_t)blockIdx.x*256 + threadIdx.x;
  ushort2* out2 = (ushort2*)out16;
  if (idx < (size_t)NX) {
    int p = (int)idx;
    ushort2 xp = xws[p];
    u16 nxt = (p + 1 < NX) ? xws[p + 1].x
                           : h2bf((u16)(zws[0] & 0xffffu));
    out2[p + 1] = make_ushort2(xp.y, nxt);
    if (p == 0) out16[1] = xp.x;
  } else {
    size_t q = idx - (size_t)NX;
    u32 zq = zws[q];
    u16 zim = h2bf((u16)(zq >> 16));
    if (q + 1 < NZQ) {
      u16 zre_next = h2bf((u16)(zws[q + 1] & 0xffffu));
      out2[(size_t)262145 + q] = make_ushort2(zim, zre_next);
    } else {
      out16[(size_t)2*NX + 2*NZQ] = zim;
    }
  }
}

extern "C" void kernel_launch(void* const* d_in, const int* in_sizes, int n_in,
                              void* d_out, int out_size, void* d_ws, size_t ws_size,
                              hipStream_t stream) {
  const float* yre  = (const float*)d_in[0];
  const float* yim  = (const float*)d_in[1];
  const float* Awre = (const float*)d_in[2];
  const float* Awim = (const float*)d_in[3];
  const float* Bwre = (const float*)d_in[4];
  const float* Bwim = (const float*)d_in[5];
  const float* t    = (const float*)d_in[6];

  // Working state in d_ws:
  //   [0, 64MB)        : z packed f16 (re,im) per pixel, u32 [4,64,256,256]
  //   [64MB, 64MB+1MB) : xhat bf16 ushort2
  u32*     zws = (u32*)d_ws;
  ushort2* xws = (ushort2*)((char*)d_ws + (size_t)67108864);

  // Scratch in d_out head (all dead before emit):
  //   [0, 8MB)     : convT residual fp32 partials (4 splits x 4 b x HW float2)
  //   [8MB, 16MB)  : convT final fp32 partials
  //   [16MB,+32)   : mean ; [16MB+64, +2112) : part
  //   [17MB,+74KB) : wA packed f16 weights ; [18MB,+74KB): wB
  //   [19MB, +1MB) : rq packed f16 residual
  char* ob = (char*)d_out;
  float2* rpart = (float2*)ob;
  float2* xpart = (float2*)(ob + 8388608);
  float2* mean  = (float2*)(ob + 16777216);
  float2* part  = (float2*)(ob + 16777280);
  uint2*  wA    = (uint2*)(ob + 17825792);
  uint2*  wB    = (uint2*)(ob + 18874368);
  u32*    rq    = (u32*)(ob + 19922944);

  wprep_kernel<<<(NTAP + 255)/256, 256, 0, stream>>>(Awre, Awim, Bwre, Bwim, wA, wB);
  mean_stage1<<<256, 256, 0, stream>>>(yre, yim, part);
  mean_stage2<<<1, 256, 0, stream>>>(part, mean);

  dim3 grid1k(NB * (Hh/PT) * (Ww/PT) * NSPL);  // 1024 blocks
  conv_first_kernel<<<grid1k, 256, 0, stream>>>(yre, yim, mean, wA, t, zws);
  for (int k = 1; k < 3; ++k) {
    convT_part_kernel<<<grid1k, 256, 0, stream>>>(zws, wB, k, rpart);
    rfold_kernel<<<NX/256, 256, 0, stream>>>(rpart, yre, yim, mean, rq);
    conv_update_kernel<<<grid1k, 256, 0, stream>>>(rq, wA, t, k, zws);
  }
  convT_part_kernel<<<grid1k, 256, 0, stream>>>(zws, wB, 0, xpart);
  xreduce_kernel<<<NX/256, 256, 0, stream>>>(xpart, mean, xws);

  size_t total = (size_t)NX + NZQ;
  emit_kernel<<<(unsigned)(total/256), 256, 0, stream>>>(xws, zws, (u16*)d_out);
}

// Round 27
// 474.727 us; speedup vs baseline: 1.4225x; 1.4225x over previous
//
#include <hip/hip_runtime.h>

#define Hh 256
#define Ww 256
#define NB 4
#define NM 64
#define KP 7
#define HW (Hh*Ww)
#define NX (NB*HW)                 // 262144 xhat pixels
#define NZQ ((size_t)NB*NM*HW)     // 16777216 z pixels
#define PT 32                      // px tile (32x32)
#define TW2 38                     // PT + 6 halo
#define LDS2 40                    // padded stride
#define NST 6                      // staging slots per thread
#define NTAP (3*NM*49)             // 9408 weight taps per array
#define NSPL 4                     // channel splits (16 ch per block)

typedef unsigned short u16;
typedef unsigned int u32;

__device__ __forceinline__ float bf2f(u16 u) {
  union { u32 i; float f; } c; c.i = ((u32)u) << 16; return c.f;
}
__device__ __forceinline__ u16 f2bf(float f) {
  union { float f; u32 i; } c; c.f = f;
  return (u16)((c.i + 0x7FFFu + ((c.i >> 16) & 1u)) >> 16);   // RNE
}
__device__ __forceinline__ ushort2 packbf(float x, float y) {
  return make_ushort2(f2bf(x), f2bf(y));
}

// ---- f16 pair helpers (packed complex value in one dword: low=re, high=im) ----
__device__ __forceinline__ u32 packh(float x, float y) {
  union { u32 u; _Float16 h[2]; } c;
  c.h[0] = (_Float16)x; c.h[1] = (_Float16)y;
  return c.u;
}
__device__ __forceinline__ float2 unpackh(u32 v) {
  union { u32 u; _Float16 h[2]; } c; c.u = v;
  return make_float2((float)c.h[0], (float)c.h[1]);
}
__device__ __forceinline__ u16 h2bf(u16 hraw) {
  union { u16 u; _Float16 h; } c; c.u = hraw;
  return f2bf((float)c.h);
}

#if __has_builtin(__builtin_amdgcn_fdot2)
typedef _Float16 hf2 __attribute__((ext_vector_type(2)));
__device__ __forceinline__ void cmac2(float& ar, float& ai, u32 v, u32 wre, u32 wim) {
  union { u32 u; hf2 h; } a, b, c;
  a.u = v; b.u = wre; c.u = wim;
  ar = __builtin_amdgcn_fdot2(a.h, b.h, ar, false);
  ai = __builtin_amdgcn_fdot2(a.h, c.h, ai, false);
}
#else
__device__ __forceinline__ void cmac2(float& ar, float& ai, u32 v, u32 wre, u32 wim) {
  float2 a = unpackh(v), b = unpackh(wre), c = unpackh(wim);
  ar = fmaf(a.x, b.x, ar); ar = fmaf(a.y, b.y, ar);
  ai = fmaf(a.x, c.x, ai); ai = fmaf(a.y, c.y, ai);
}
#endif

// soft-threshold factor: max(1 - t*rsqrt(s), 0), s = re^2+im^2.
// s=0 -> rsqrt=inf -> (t>0: -inf, t=0: NaN) -> fmaxf returns 0. Correct.
__device__ __forceinline__ float stfac(float s, float t) {
  return fmaxf(1.f - t*rsqrtf(s), 0.f);
}

// ---------------- weight prep: pack (wr,-wi),(wi,wr) as f16 pairs ----------------
__global__ __launch_bounds__(256) void wprep_kernel(
    const float* __restrict__ Awre, const float* __restrict__ Awim,
    const float* __restrict__ Bwre, const float* __restrict__ Bwim,
    uint2* __restrict__ wA, uint2* __restrict__ wB) {
  int i = blockIdx.x*256 + threadIdx.x;
  if (i < NTAP) {
    float wr = Awre[i], wi = Awim[i];
    wA[i] = make_uint2(packh(wr, -wi), packh(wi, wr));
    wr = Bwre[i]; wi = Bwim[i];
    wB[i] = make_uint2(packh(wr, -wi), packh(wi, wr));
  }
}

// ---------------- mean over (C,H,W) per batch, complex ----------------
__global__ __launch_bounds__(256) void mean_stage1(
    const float* __restrict__ yre, const float* __restrict__ yim,
    float2* __restrict__ part) {
  int blk = blockIdx.x;           // 256 blocks: 64 per batch
  int b = blk >> 6, chunk = blk & 63;
  int tid = threadIdx.x;
  int base = b*HW + chunk*1024;
  float sr = 0.f, si = 0.f;
  #pragma unroll
  for (int j = 0; j < 4; ++j) {
    sr += yre[base + tid + j*256];
    si += yim[base + tid + j*256];
  }
  #pragma unroll
  for (int off = 32; off > 0; off >>= 1) {
    sr += __shfl_down(sr, off);
    si += __shfl_down(si, off);
  }
  __shared__ float2 red[4];
  if ((tid & 63) == 0) red[tid >> 6] = make_float2(sr, si);
  __syncthreads();
  if (tid == 0) {
    float2 a = red[0], b2 = red[1], c = red[2], d = red[3];
    part[blk] = make_float2(a.x + b2.x + c.x + d.x, a.y + b2.y + c.y + d.y);
  }
}

__global__ __launch_bounds__(256) void mean_stage2(
    const float2* __restrict__ part, float2* __restrict__ mean) {
  int tid = threadIdx.x;
  int b = tid >> 6, lane = tid & 63;
  float2 v = part[b*64 + lane];
  float sr = v.x, si = v.y;
  #pragma unroll
  for (int off = 32; off > 0; off >>= 1) {
    sr += __shfl_down(sr, off);
    si += __shfl_down(si, off);
  }
  if (lane == 0) mean[b] = make_float2(sr / (float)HW, si / (float)HW);
}

// ---------------- z0 = ST(conv(yp, A0), t[0,0]) — 16ch/block, 4ch/group ----------------
__global__ __launch_bounds__(256) void conv_first_kernel(
    const float* __restrict__ yre, const float* __restrict__ yim,
    const float2* __restrict__ mean,
    const uint2* __restrict__ wA,
    const float* __restrict__ t, u32* __restrict__ z) {
  int tid = threadIdx.x;
  int blk = blockIdx.x;                 // 1024 = ms + 4*(txi + 8*(tyi + 8*b))
  int ms  = blk & 3;
  int txi = (blk >> 2) & 7, tyi = (blk >> 5) & 7, b = (blk >> 8) & 3;
  int ty0 = tyi*PT, tx0 = txi*PT;
  int thy = tid >> 4, thx = tid & 15;

  __shared__ u32 tile[TW2][LDS2];
  float2 mb = mean[b];
  const float* re = yre + b*HW;
  const float* im = yim + b*HW;
  for (int i = tid; i < TW2*TW2; i += 256) {
    int rr = i / TW2, cc = i - rr*TW2;
    int gy = ty0 - 3 + rr, gx = tx0 - 3 + cc;
    u32 v = 0;
    if ((unsigned)gy < Hh && (unsigned)gx < Ww) {
      int o = gy*Ww + gx;
      v = packh(re[o] - mb.x, im[o] - mb.y);
    }
    tile[rr][cc] = v;
  }
  __syncthreads();

  u32* zb = z + ((size_t)b*NM << 16);
  int m0 = ms*16;
  #pragma unroll 1
  for (int mm = 0; mm < 16; mm += 4) {
    int m = m0 + mm;
    const uint2* w0p = wA + m*49;       // k = 0
    float ar[4][4], ai[4][4];
    #pragma unroll
    for (int c = 0; c < 4; ++c)
      #pragma unroll
      for (int p = 0; p < 4; ++p) { ar[c][p] = 0.f; ai[c][p] = 0.f; }
    #pragma unroll
    for (int ky = 0; ky < KP; ++ky) {
      #pragma unroll
      for (int kx = 0; kx < KP; ++kx) {
        int wo = ky*KP + kx;
        uint2 w0 = w0p[wo], w1 = w0p[49 + wo], w2 = w0p[98 + wo], w3 = w0p[147 + wo];
        #pragma unroll
        for (int dy = 0; dy < 2; ++dy) {
          #pragma unroll
          for (int dx = 0; dx < 2; ++dx) {
            u32 v = tile[thy + dy*16 + ky][thx + dx*16 + kx];
            int p = dy*2 + dx;
            cmac2(ar[0][p], ai[0][p], v, w0.x, w0.y);
            cmac2(ar[1][p], ai[1][p], v, w1.x, w1.y);
            cmac2(ar[2][p], ai[2][p], v, w2.x, w2.y);
            cmac2(ar[3][p], ai[3][p], v, w3.x, w3.y);
          }
        }
      }
    }
    #pragma unroll
    for (int c = 0; c < 4; ++c) {
      float tc = t[m + c];              // t[0,0,m+c]
      #pragma unroll
      for (int dy = 0; dy < 2; ++dy) {
        #pragma unroll
        for (int dx = 0; dx < 2; ++dx) {
          int p = dy*2 + dx;
          size_t o = (size_t)(ty0 + thy + dy*16)*Ww + tx0 + thx + dx*16;
          float s = ar[c][p]*ar[c][p] + ai[c][p]*ai[c][p];
          float f = stfac(s, tc);
          zb[((size_t)(m + c) << 16) + o] = packh(ar[c][p]*f, ai[c][p]*f);
        }
      }
    }
  }
}

// ---------------- partial convT over 16 ch (4ch packed uint4, single-buffer) ----------------
__global__ __launch_bounds__(256) void convT_part_kernel(
    const u32* __restrict__ z,
    const uint2* __restrict__ wB,
    int k, float2* __restrict__ rpart) {
  int tid = threadIdx.x;
  int blk = blockIdx.x;                 // 1024 = s + 4*(txi + 8*(tyi + 8*b))
  int s   = blk & 3;
  int txi = (blk >> 2) & 7, tyi = (blk >> 5) & 7, b = (blk >> 8) & 3;
  int ty0 = tyi*PT, tx0 = txi*PT;
  int thy = tid >> 4, thx = tid & 15;

  __shared__ uint4 tile[TW2][LDS2];     // 4 consecutive channels per element (24320 B)

  int srr[NST], scc[NST], soff[NST];
  bool sok[NST], sin[NST];
  #pragma unroll
  for (int j = 0; j < NST; ++j) {
    int i = tid + j*256;
    sin[j] = i < TW2*TW2;
    int rr = sin[j] ? i / TW2 : 0;
    int cc = sin[j] ? i - rr*TW2 : 0;
    int gy = ty0 - 3 + rr, gx = tx0 - 3 + cc;
    sok[j] = sin[j] && (unsigned)gy < Hh && (unsigned)gx < Ww;
    srr[j] = rr; scc[j] = cc;
    soff[j] = sok[j] ? gy*Ww + gx : 0;
  }

  const u32* zb = z + ((size_t)b*NM << 16);
  int m0 = s*16;

  float ar[4] = {0.f,0.f,0.f,0.f}, ai[4] = {0.f,0.f,0.f,0.f};
  #pragma unroll 1
  for (int q = 0; q < 4; ++q) {         // 4 channel quads
    int m = m0 + 4*q;
    if (q) __syncthreads();             // protect previous iteration's reads
    {
      const u32* z0 = zb + ((size_t)m << 16);
      const u32* z1 = zb + ((size_t)(m + 1) << 16);
      const u32* z2 = zb + ((size_t)(m + 2) << 16);
      const u32* z3 = zb + ((size_t)(m + 3) << 16);
      #pragma unroll
      for (int j = 0; j < NST; ++j)
        if (sin[j]) tile[srr[j]][scc[j]] = make_uint4(
          sok[j] ? z0[soff[j]] : 0u, sok[j] ? z1[soff[j]] : 0u,
          sok[j] ? z2[soff[j]] : 0u, sok[j] ? z3[soff[j]] : 0u);
    }
    __syncthreads();

    const uint2* w0p = wB + (k*NM + m)*49;
    #pragma unroll
    for (int ky = 0; ky < KP; ++ky) {
      #pragma unroll
      for (int kx = 0; kx < KP; ++kx) {
        int wo = ky*KP + kx;
        uint2 wa = w0p[wo], wb = w0p[49 + wo], wc = w0p[98 + wo], wd = w0p[147 + wo];
        #pragma unroll
        for (int dy = 0; dy < 2; ++dy) {
          #pragma unroll
          for (int dx = 0; dx < 2; ++dx) {
            uint4 v = tile[thy + dy*16 + 6 - ky][thx + dx*16 + 6 - kx];
            int p = dy*2 + dx;
            cmac2(ar[p], ai[p], v.x, wa.x, wa.y);
            cmac2(ar[p], ai[p], v.y, wb.x, wb.y);
            cmac2(ar[p], ai[p], v.z, wc.x, wc.y);
            cmac2(ar[p], ai[p], v.w, wd.x, wd.y);
          }
        }
      }
    }
  }

  float2* rp = rpart + (size_t)s*NB*HW + (size_t)b*HW;
  #pragma unroll
  for (int dy = 0; dy < 2; ++dy) {
    #pragma unroll
    for (int dx = 0; dx < 2; ++dx) {
      int p = dy*2 + dx;
      int o = (ty0 + thy + dy*16)*Ww + tx0 + thx + dx*16;
      rp[o] = make_float2(ar[p], ai[p]);
    }
  }
}

// ---------------- rfold: rq = packh(Σ4 rpart − (y − mean)) ----------------
__global__ __launch_bounds__(256) void rfold_kernel(
    const float2* __restrict__ rpart,
    const float* __restrict__ yre, const float* __restrict__ yim,
    const float2* __restrict__ mean, u32* __restrict__ rq) {
  int p = blockIdx.x*256 + threadIdx.x;   // 0..NX (p = b*HW + px)
  int b = p >> 16;
  float2 mb = mean[b];
  float2 p0 = rpart[p];
  float2 p1 = rpart[(size_t)NB*HW + p];
  float2 p2 = rpart[(size_t)2*NB*HW + p];
  float2 p3 = rpart[(size_t)3*NB*HW + p];
  rq[p] = packh(p0.x + p1.x + p2.x + p3.x - (yre[p] - mb.x),
                p0.y + p1.y + p2.y + p3.y - (yim[p] - mb.y));
}

// ---------------- z = ST(z - conv(rq, A[k]), t[k,0]) — 16ch/block, 4ch/group ----------------
__global__ __launch_bounds__(256) void conv_update_kernel(
    const u32* __restrict__ rq,
    const uint2* __restrict__ wA,
    const float* __restrict__ t, int k, u32* __restrict__ z) {
  int tid = threadIdx.x;
  int blk = blockIdx.x;                 // 1024 = ms + 4*(txi + 8*(tyi + 8*b))
  int ms  = blk & 3;
  int txi = (blk >> 2) & 7, tyi = (blk >> 5) & 7, b = (blk >> 8) & 3;
  int ty0 = tyi*PT, tx0 = txi*PT;
  int thy = tid >> 4, thx = tid & 15;

  __shared__ u32 tile[TW2][LDS2];
  const u32* rb = rq + b*HW;
  for (int i = tid; i < TW2*TW2; i += 256) {
    int rr = i / TW2, cc = i - rr*TW2;
    int gy = ty0 - 3 + rr, gx = tx0 - 3 + cc;
    u32 v = 0;
    if ((unsigned)gy < Hh && (unsigned)gx < Ww) v = rb[gy*Ww + gx];
    tile[rr][cc] = v;
  }
  __syncthreads();

  const float* tw = t + k*2*NM;         // t[k,0,:]
  u32* zb = z + ((size_t)b*NM << 16);
  int m0 = ms*16;
  #pragma unroll 1
  for (int mm = 0; mm < 16; mm += 4) {
    int m = m0 + mm;
    const uint2* w0p = wA + (k*NM + m)*49;
    float ar[4][4], ai[4][4];
    #pragma unroll
    for (int c = 0; c < 4; ++c)
      #pragma unroll
      for (int p = 0; p < 4; ++p) { ar[c][p] = 0.f; ai[c][p] = 0.f; }
    #pragma unroll
    for (int ky = 0; ky < KP; ++ky) {
      #pragma unroll
      for (int kx = 0; kx < KP; ++kx) {
        int wo = ky*KP + kx;
        uint2 w0 = w0p[wo], w1 = w0p[49 + wo], w2 = w0p[98 + wo], w3 = w0p[147 + wo];
        #pragma unroll
        for (int dy = 0; dy < 2; ++dy) {
          #pragma unroll
          for (int dx = 0; dx < 2; ++dx) {
            u32 v = tile[thy + dy*16 + ky][thx + dx*16 + kx];
            int p = dy*2 + dx;
            cmac2(ar[0][p], ai[0][p], v, w0.x, w0.y);
            cmac2(ar[1][p], ai[1][p], v, w1.x, w1.y);
            cmac2(ar[2][p], ai[2][p], v, w2.x, w2.y);
            cmac2(ar[3][p], ai[3][p], v, w3.x, w3.y);
          }
        }
      }
    }
    #pragma unroll
    for (int c = 0; c < 4; ++c) {
      float tc = tw[m + c];
      #pragma unroll
      for (int dy = 0; dy < 2; ++dy) {
        #pragma unroll
        for (int dx = 0; dx < 2; ++dx) {
          int p = dy*2 + dx;
          size_t o = (size_t)(ty0 + thy + dy*16)*Ww + tx0 + thx + dx*16;
          size_t q0 = ((size_t)(m + c) << 16) + o;
          float2 z0 = unpackh(zb[q0]);
          float zr0 = z0.x - ar[c][p], zi0 = z0.y - ai[c][p];
          float s = zr0*zr0 + zi0*zi0;
          float f = stfac(s, tc);
          zb[q0] = packh(zr0*f, zi0*f);
        }
      }
    }
  }
}

// ---------------- xhat partial reduce: xws = bf16(Σx + mean) ----------------
__global__ __launch_bounds__(256) void xreduce_kernel(
    const float2* __restrict__ xpart,
    const float2* __restrict__ mean, ushort2* __restrict__ xws) {
  int p = blockIdx.x*256 + threadIdx.x;   // 0..NX
  int b = p >> 16;
  float2 mb = mean[b];
  float2 a0 = xpart[p];
  float2 a1 = xpart[(size_t)NB*HW + p];
  float2 a2 = xpart[(size_t)2*NB*HW + p];
  float2 a3 = xpart[(size_t)3*NB*HW + p];
  xws[p] = packbf(a0.x + a1.x + a2.x + a3.x + mb.x,
                  a0.y + a1.y + a2.y + a3.y + mb.y);
}

// ---------------- emit: shifted (+1 element) copy into d_out; z f16->bf16 ----------------
__global__ __launch_bounds__(256) void emit_kernel(
    const ushort2* __restrict__ xws, const u32* __restrict__ zws,
    u16* __restrict__ out16) {
  size_t idx = (size_t)blockIdx.x*256 + threadIdx.x;
  ushort2* out2 = (ushort2*)out16;
  if (idx < (size_t)NX) {
    int p = (int)idx;
    ushort2 xp = xws[p];
    u16 nxt = (p + 1 < NX) ? xws[p + 1].x
                           : h2bf((u16)(zws[0] & 0xffffu));
    out2[p + 1] = make_ushort2(xp.y, nxt);
    if (p == 0) out16[1] = xp.x;
  } else {
    size_t q = idx - (size_t)NX;
    u32 zq = zws[q];
    u16 zim = h2bf((u16)(zq >> 16));
    if (q + 1 < NZQ) {
      u16 zre_next = h2bf((u16)(zws[q + 1] & 0xffffu));
      out2[(size_t)262145 + q] = make_ushort2(zim, zre_next);
    } else {
      out16[(size_t)2*NX + 2*NZQ] = zim;
    }
  }
}

extern "C" void kernel_launch(void* const* d_in, const int* in_sizes, int n_in,
                              void* d_out, int out_size, void* d_ws, size_t ws_size,
                              hipStream_t stream) {
  const float* yre  = (const float*)d_in[0];
  const float* yim  = (const float*)d_in[1];
  const float* Awre = (const float*)d_in[2];
  const float* Awim = (const float*)d_in[3];
  const float* Bwre = (const float*)d_in[4];
  const float* Bwim = (const float*)d_in[5];
  const float* t    = (const float*)d_in[6];

  // Working state in d_ws:
  //   [0, 64MB)        : z packed f16 (re,im) per pixel, u32 [4,64,256,256]
  //   [64MB, 64MB+1MB) : xhat bf16 ushort2
  u32*     zws = (u32*)d_ws;
  ushort2* xws = (ushort2*)((char*)d_ws + (size_t)67108864);

  // Scratch in d_out head (all dead before emit):
  //   [0, 8MB)     : convT residual fp32 partials (4 splits x 4 b x HW float2)
  //   [8MB, 16MB)  : convT final fp32 partials
  //   [16MB,+32)   : mean ; [16MB+64, +2112) : part
  //   [17MB,+74KB) : wA packed f16 weights ; [18MB,+74KB): wB
  //   [19MB, +1MB) : rq packed f16 residual
  char* ob = (char*)d_out;
  float2* rpart = (float2*)ob;
  float2* xpart = (float2*)(ob + 8388608);
  float2* mean  = (float2*)(ob + 16777216);
  float2* part  = (float2*)(ob + 16777280);
  uint2*  wA    = (uint2*)(ob + 17825792);
  uint2*  wB    = (uint2*)(ob + 18874368);
  u32*    rq    = (u32*)(ob + 19922944);

  wprep_kernel<<<(NTAP + 255)/256, 256, 0, stream>>>(Awre, Awim, Bwre, Bwim, wA, wB);
  mean_stage1<<<256, 256, 0, stream>>>(yre, yim, part);
  mean_stage2<<<1, 256, 0, stream>>>(part, mean);

  dim3 grid1k(NB * (Hh/PT) * (Ww/PT) * NSPL);  // 1024 blocks
  conv_first_kernel<<<grid1k, 256, 0, stream>>>(yre, yim, mean, wA, t, zws);
  for (int k = 1; k < 3; ++k) {
    convT_part_kernel<<<grid1k, 256, 0, stream>>>(zws, wB, k, rpart);
    rfold_kernel<<<NX/256, 256, 0, stream>>>(rpart, yre, yim, mean, rq);
    conv_update_kernel<<<grid1k, 256, 0, stream>>>(rq, wA, t, k, zws);
  }
  convT_part_kernel<<<grid1k, 256, 0, stream>>>(zws, wB, 0, xpart);
  xreduce_kernel<<<NX/256, 256, 0, stream>>>(xpart, mean, xws);

  size_t total = (size_t)NX + NZQ;
  emit_kernel<<<(unsigned)(total/256), 256, 0, stream>>>(xws, zws, (u16*)d_out);
}

// Round 28
// 452.169 us; speedup vs baseline: 1.4934x; 1.0499x over previous
//
#include <hip/hip_runtime.h>

#define Hh 256
#define Ww 256
#define NB 4
#define NM 64
#define KP 7
#define HW (Hh*Ww)
#define NX (NB*HW)                 // 262144 xhat pixels
#define NZQ ((size_t)NB*NM*HW)     // 16777216 z pixels
// convT tiles (R27-proven)
#define PT 32
#define TW2 38
#define LDS2 40
#define NST 6
// A-conv tiles (R28): 16 rows x 32 cols, 2 px/thread
#define ATY 16
#define ATX 32
#define ATWY 22
#define ATWX 38
#define ALDS 40
#define NTAP (3*NM*49)             // 9408 weight taps per array
#define NSPL 4                     // channel splits (16 ch per block)

typedef unsigned short u16;
typedef unsigned int u32;

__device__ __forceinline__ float bf2f(u16 u) {
  union { u32 i; float f; } c; c.i = ((u32)u) << 16; return c.f;
}
__device__ __forceinline__ u16 f2bf(float f) {
  union { float f; u32 i; } c; c.f = f;
  return (u16)((c.i + 0x7FFFu + ((c.i >> 16) & 1u)) >> 16);   // RNE
}
__device__ __forceinline__ ushort2 packbf(float x, float y) {
  return make_ushort2(f2bf(x), f2bf(y));
}

// ---- f16 pair helpers (packed complex value in one dword: low=re, high=im) ----
__device__ __forceinline__ u32 packh(float x, float y) {
  union { u32 u; _Float16 h[2]; } c;
  c.h[0] = (_Float16)x; c.h[1] = (_Float16)y;
  return c.u;
}
__device__ __forceinline__ float2 unpackh(u32 v) {
  union { u32 u; _Float16 h[2]; } c; c.u = v;
  return make_float2((float)c.h[0], (float)c.h[1]);
}
__device__ __forceinline__ u16 h2bf(u16 hraw) {
  union { u16 u; _Float16 h; } c; c.u = hraw;
  return f2bf((float)c.h);
}

#if __has_builtin(__builtin_amdgcn_fdot2)
typedef _Float16 hf2 __attribute__((ext_vector_type(2)));
__device__ __forceinline__ void cmac2(float& ar, float& ai, u32 v, u32 wre, u32 wim) {
  union { u32 u; hf2 h; } a, b, c;
  a.u = v; b.u = wre; c.u = wim;
  ar = __builtin_amdgcn_fdot2(a.h, b.h, ar, false);
  ai = __builtin_amdgcn_fdot2(a.h, c.h, ai, false);
}
#else
__device__ __forceinline__ void cmac2(float& ar, float& ai, u32 v, u32 wre, u32 wim) {
  float2 a = unpackh(v), b = unpackh(wre), c = unpackh(wim);
  ar = fmaf(a.x, b.x, ar); ar = fmaf(a.y, b.y, ar);
  ai = fmaf(a.x, c.x, ai); ai = fmaf(a.y, c.y, ai);
}
#endif

// soft-threshold factor: max(1 - t*rsqrt(s), 0), s = re^2+im^2.
__device__ __forceinline__ float stfac(float s, float t) {
  return fmaxf(1.f - t*rsqrtf(s), 0.f);
}

// ---------------- weight prep: pack (wr,-wi),(wi,wr) as f16 pairs ----------------
__global__ __launch_bounds__(256) void wprep_kernel(
    const float* __restrict__ Awre, const float* __restrict__ Awim,
    const float* __restrict__ Bwre, const float* __restrict__ Bwim,
    uint2* __restrict__ wA, uint2* __restrict__ wB) {
  int i = blockIdx.x*256 + threadIdx.x;
  if (i < NTAP) {
    float wr = Awre[i], wi = Awim[i];
    wA[i] = make_uint2(packh(wr, -wi), packh(wi, wr));
    wr = Bwre[i]; wi = Bwim[i];
    wB[i] = make_uint2(packh(wr, -wi), packh(wi, wr));
  }
}

// ---------------- mean over (C,H,W) per batch, complex ----------------
__global__ __launch_bounds__(256) void mean_stage1(
    const float* __restrict__ yre, const float* __restrict__ yim,
    float2* __restrict__ part) {
  int blk = blockIdx.x;           // 256 blocks: 64 per batch
  int b = blk >> 6, chunk = blk & 63;
  int tid = threadIdx.x;
  int base = b*HW + chunk*1024;
  float sr = 0.f, si = 0.f;
  #pragma unroll
  for (int j = 0; j < 4; ++j) {
    sr += yre[base + tid + j*256];
    si += yim[base + tid + j*256];
  }
  #pragma unroll
  for (int off = 32; off > 0; off >>= 1) {
    sr += __shfl_down(sr, off);
    si += __shfl_down(si, off);
  }
  __shared__ float2 red[4];
  if ((tid & 63) == 0) red[tid >> 6] = make_float2(sr, si);
  __syncthreads();
  if (tid == 0) {
    float2 a = red[0], b2 = red[1], c = red[2], d = red[3];
    part[blk] = make_float2(a.x + b2.x + c.x + d.x, a.y + b2.y + c.y + d.y);
  }
}

__global__ __launch_bounds__(256) void mean_stage2(
    const float2* __restrict__ part, float2* __restrict__ mean) {
  int tid = threadIdx.x;
  int b = tid >> 6, lane = tid & 63;
  float2 v = part[b*64 + lane];
  float sr = v.x, si = v.y;
  #pragma unroll
  for (int off = 32; off > 0; off >>= 1) {
    sr += __shfl_down(sr, off);
    si += __shfl_down(si, off);
  }
  if (lane == 0) mean[b] = make_float2(sr / (float)HW, si / (float)HW);
}

// ---------------- z0 = ST(conv(yp, A0), t[0,0]) — 16ch/block, 8ch/group, 2px ----------------
__global__ __launch_bounds__(256) void conv_first_kernel(
    const float* __restrict__ yre, const float* __restrict__ yim,
    const float2* __restrict__ mean,
    const uint2* __restrict__ wA,
    const float* __restrict__ t, u32* __restrict__ z) {
  int tid = threadIdx.x;
  int blk = blockIdx.x;                 // 2048 = ms + 4*(txi + 8*(tyi + 16*b))
  int ms  = blk & 3;
  int txi = (blk >> 2) & 7, tyi = (blk >> 5) & 15, b = (blk >> 9) & 3;
  int ty0 = tyi*ATY, tx0 = txi*ATX;
  int thy = tid >> 4, thx = tid & 15;

  __shared__ u32 tile[ATWY][ALDS];
  float2 mb = mean[b];
  const float* re = yre + b*HW;
  const float* im = yim + b*HW;
  for (int i = tid; i < ATWY*ATWX; i += 256) {
    int rr = i / ATWX, cc = i - rr*ATWX;
    int gy = ty0 - 3 + rr, gx = tx0 - 3 + cc;
    u32 v = 0;
    if ((unsigned)gy < Hh && (unsigned)gx < Ww) {
      int o = gy*Ww + gx;
      v = packh(re[o] - mb.x, im[o] - mb.y);
    }
    tile[rr][cc] = v;
  }
  __syncthreads();

  u32* zb = z + ((size_t)b*NM << 16);
  int m0 = ms*16;
  #pragma unroll 1
  for (int mm = 0; mm < 16; mm += 8) {
    int m = m0 + mm;
    const uint2* w0p = wA + m*49;       // k = 0
    float ar[8][2], ai[8][2];
    #pragma unroll
    for (int c = 0; c < 8; ++c) {
      ar[c][0] = 0.f; ar[c][1] = 0.f; ai[c][0] = 0.f; ai[c][1] = 0.f;
    }
    #pragma unroll
    for (int ky = 0; ky < KP; ++ky) {
      #pragma unroll
      for (int kx = 0; kx < KP; ++kx) {
        int wo = ky*KP + kx;
        u32 v0 = tile[thy + ky][thx + kx];
        u32 v1 = tile[thy + ky][thx + 16 + kx];
        #pragma unroll
        for (int c = 0; c < 8; ++c) {
          uint2 w = w0p[c*49 + wo];
          cmac2(ar[c][0], ai[c][0], v0, w.x, w.y);
          cmac2(ar[c][1], ai[c][1], v1, w.x, w.y);
        }
      }
    }
    #pragma unroll
    for (int c = 0; c < 8; ++c) {
      float tc = t[m + c];              // t[0,0,m+c]
      #pragma unroll
      for (int p = 0; p < 2; ++p) {
        size_t o = (size_t)(ty0 + thy)*Ww + tx0 + thx + p*16;
        float s = ar[c][p]*ar[c][p] + ai[c][p]*ai[c][p];
        float f = stfac(s, tc);
        zb[((size_t)(m + c) << 16) + o] = packh(ar[c][p]*f, ai[c][p]*f);
      }
    }
  }
}

// ---------------- partial convT over 16 ch (4ch packed uint4, single-buffer) ----------------
__global__ __launch_bounds__(256) void convT_part_kernel(
    const u32* __restrict__ z,
    const uint2* __restrict__ wB,
    int k, float2* __restrict__ rpart) {
  int tid = threadIdx.x;
  int blk = blockIdx.x;                 // 1024 = s + 4*(txi + 8*(tyi + 8*b))
  int s   = blk & 3;
  int txi = (blk >> 2) & 7, tyi = (blk >> 5) & 7, b = (blk >> 8) & 3;
  int ty0 = tyi*PT, tx0 = txi*PT;
  int thy = tid >> 4, thx = tid & 15;

  __shared__ uint4 tile[TW2][LDS2];     // 4 consecutive channels per element

  int srr[NST], scc[NST], soff[NST];
  bool sok[NST], sin[NST];
  #pragma unroll
  for (int j = 0; j < NST; ++j) {
    int i = tid + j*256;
    sin[j] = i < TW2*TW2;
    int rr = sin[j] ? i / TW2 : 0;
    int cc = sin[j] ? i - rr*TW2 : 0;
    int gy = ty0 - 3 + rr, gx = tx0 - 3 + cc;
    sok[j] = sin[j] && (unsigned)gy < Hh && (unsigned)gx < Ww;
    srr[j] = rr; scc[j] = cc;
    soff[j] = sok[j] ? gy*Ww + gx : 0;
  }

  const u32* zb = z + ((size_t)b*NM << 16);
  int m0 = s*16;

  float ar[4] = {0.f,0.f,0.f,0.f}, ai[4] = {0.f,0.f,0.f,0.f};
  #pragma unroll 1
  for (int q = 0; q < 4; ++q) {         // 4 channel quads
    int m = m0 + 4*q;
    if (q) __syncthreads();             // protect previous iteration's reads
    {
      const u32* z0 = zb + ((size_t)m << 16);
      const u32* z1 = zb + ((size_t)(m + 1) << 16);
      const u32* z2 = zb + ((size_t)(m + 2) << 16);
      const u32* z3 = zb + ((size_t)(m + 3) << 16);
      #pragma unroll
      for (int j = 0; j < NST; ++j)
        if (sin[j]) tile[srr[j]][scc[j]] = make_uint4(
          sok[j] ? z0[soff[j]] : 0u, sok[j] ? z1[soff[j]] : 0u,
          sok[j] ? z2[soff[j]] : 0u, sok[j] ? z3[soff[j]] : 0u);
    }
    __syncthreads();

    const uint2* w0p = wB + (k*NM + m)*49;
    #pragma unroll
    for (int ky = 0; ky < KP; ++ky) {
      #pragma unroll
      for (int kx = 0; kx < KP; ++kx) {
        int wo = ky*KP + kx;
        uint2 wa = w0p[wo], wb = w0p[49 + wo], wc = w0p[98 + wo], wd = w0p[147 + wo];
        #pragma unroll
        for (int dy = 0; dy < 2; ++dy) {
          #pragma unroll
          for (int dx = 0; dx < 2; ++dx) {
            uint4 v = tile[thy + dy*16 + 6 - ky][thx + dx*16 + 6 - kx];
            int p = dy*2 + dx;
            cmac2(ar[p], ai[p], v.x, wa.x, wa.y);
            cmac2(ar[p], ai[p], v.y, wb.x, wb.y);
            cmac2(ar[p], ai[p], v.z, wc.x, wc.y);
            cmac2(ar[p], ai[p], v.w, wd.x, wd.y);
          }
        }
      }
    }
  }

  float2* rp = rpart + (size_t)s*NB*HW + (size_t)b*HW;
  #pragma unroll
  for (int dy = 0; dy < 2; ++dy) {
    #pragma unroll
    for (int dx = 0; dx < 2; ++dx) {
      int p = dy*2 + dx;
      int o = (ty0 + thy + dy*16)*Ww + tx0 + thx + dx*16;
      rp[o] = make_float2(ar[p], ai[p]);
    }
  }
}

// ---------------- rfold: rq = packh(Σ4 rpart − (y − mean)) ----------------
__global__ __launch_bounds__(256) void rfold_kernel(
    const float2* __restrict__ rpart,
    const float* __restrict__ yre, const float* __restrict__ yim,
    const float2* __restrict__ mean, u32* __restrict__ rq) {
  int p = blockIdx.x*256 + threadIdx.x;   // 0..NX (p = b*HW + px)
  int b = p >> 16;
  float2 mb = mean[b];
  float2 p0 = rpart[p];
  float2 p1 = rpart[(size_t)NB*HW + p];
  float2 p2 = rpart[(size_t)2*NB*HW + p];
  float2 p3 = rpart[(size_t)3*NB*HW + p];
  rq[p] = packh(p0.x + p1.x + p2.x + p3.x - (yre[p] - mb.x),
                p0.y + p1.y + p2.y + p3.y - (yim[p] - mb.y));
}

// ---------------- z = ST(z - conv(rq, A[k]), t[k,0]) — 16ch/block, 8ch/group, 2px ----------------
__global__ __launch_bounds__(256) void conv_update_kernel(
    const u32* __restrict__ rq,
    const uint2* __restrict__ wA,
    const float* __restrict__ t, int k, u32* __restrict__ z) {
  int tid = threadIdx.x;
  int blk = blockIdx.x;                 // 2048 = ms + 4*(txi + 8*(tyi + 16*b))
  int ms  = blk & 3;
  int txi = (blk >> 2) & 7, tyi = (blk >> 5) & 15, b = (blk >> 9) & 3;
  int ty0 = tyi*ATY, tx0 = txi*ATX;
  int thy = tid >> 4, thx = tid & 15;

  __shared__ u32 tile[ATWY][ALDS];
  const u32* rb = rq + b*HW;
  for (int i = tid; i < ATWY*ATWX; i += 256) {
    int rr = i / ATWX, cc = i - rr*ATWX;
    int gy = ty0 - 3 + rr, gx = tx0 - 3 + cc;
    u32 v = 0;
    if ((unsigned)gy < Hh && (unsigned)gx < Ww) v = rb[gy*Ww + gx];
    tile[rr][cc] = v;
  }
  __syncthreads();

  const float* tw = t + k*2*NM;         // t[k,0,:]
  u32* zb = z + ((size_t)b*NM << 16);
  int m0 = ms*16;
  #pragma unroll 1
  for (int mm = 0; mm < 16; mm += 8) {
    int m = m0 + mm;
    const uint2* w0p = wA + (k*NM + m)*49;
    float ar[8][2], ai[8][2];
    #pragma unroll
    for (int c = 0; c < 8; ++c) {
      ar[c][0] = 0.f; ar[c][1] = 0.f; ai[c][0] = 0.f; ai[c][1] = 0.f;
    }
    #pragma unroll
    for (int ky = 0; ky < KP; ++ky) {
      #pragma unroll
      for (int kx = 0; kx < KP; ++kx) {
        int wo = ky*KP + kx;
        u32 v0 = tile[thy + ky][thx + kx];
        u32 v1 = tile[thy + ky][thx + 16 + kx];
        #pragma unroll
        for (int c = 0; c < 8; ++c) {
          uint2 w = w0p[c*49 + wo];
          cmac2(ar[c][0], ai[c][0], v0, w.x, w.y);
          cmac2(ar[c][1], ai[c][1], v1, w.x, w.y);
        }
      }
    }
    #pragma unroll
    for (int c = 0; c < 8; ++c) {
      float tc = tw[m + c];
      #pragma unroll
      for (int p = 0; p < 2; ++p) {
        size_t o = (size_t)(ty0 + thy)*Ww + tx0 + thx + p*16;
        size_t q0 = ((size_t)(m + c) << 16) + o;
        float2 z0 = unpackh(zb[q0]);
        float zr0 = z0.x - ar[c][p], zi0 = z0.y - ai[c][p];
        float s = zr0*zr0 + zi0*zi0;
        float f = stfac(s, tc);
        zb[q0] = packh(zr0*f, zi0*f);
      }
    }
  }
}

// ---------------- xhat partial reduce: xws = bf16(Σx + mean) ----------------
__global__ __launch_bounds__(256) void xreduce_kernel(
    const float2* __restrict__ xpart,
    const float2* __restrict__ mean, ushort2* __restrict__ xws) {
  int p = blockIdx.x*256 + threadIdx.x;   // 0..NX
  int b = p >> 16;
  float2 mb = mean[b];
  float2 a0 = xpart[p];
  float2 a1 = xpart[(size_t)NB*HW + p];
  float2 a2 = xpart[(size_t)2*NB*HW + p];
  float2 a3 = xpart[(size_t)3*NB*HW + p];
  xws[p] = packbf(a0.x + a1.x + a2.x + a3.x + mb.x,
                  a0.y + a1.y + a2.y + a3.y + mb.y);
}

// ---------------- emit: shifted (+1 element) copy into d_out; z f16->bf16 ----------------
__global__ __launch_bounds__(256) void emit_kernel(
    const ushort2* __restrict__ xws, const u32* __restrict__ zws,
    u16* __restrict__ out16) {
  size_t idx = (size_t)blockIdx.x*256 + threadIdx.x;
  ushort2* out2 = (ushort2*)out16;
  if (idx < (size_t)NX) {
    int p = (int)idx;
    ushort2 xp = xws[p];
    u16 nxt = (p + 1 < NX) ? xws[p + 1].x
                           : h2bf((u16)(zws[0] & 0xffffu));
    out2[p + 1] = make_ushort2(xp.y, nxt);
    if (p == 0) out16[1] = xp.x;
  } else {
    size_t q = idx - (size_t)NX;
    u32 zq = zws[q];
    u16 zim = h2bf((u16)(zq >> 16));
    if (q + 1 < NZQ) {
      u16 zre_next = h2bf((u16)(zws[q + 1] & 0xffffu));
      out2[(size_t)262145 + q] = make_ushort2(zim, zre_next);
    } else {
      out16[(size_t)2*NX + 2*NZQ] = zim;
    }
  }
}

extern "C" void kernel_launch(void* const* d_in, const int* in_sizes, int n_in,
                              void* d_out, int out_size, void* d_ws, size_t ws_size,
                              hipStream_t stream) {
  const float* yre  = (const float*)d_in[0];
  const float* yim  = (const float*)d_in[1];
  const float* Awre = (const float*)d_in[2];
  const float* Awim = (const float*)d_in[3];
  const float* Bwre = (const float*)d_in[4];
  const float* Bwim = (const float*)d_in[5];
  const float* t    = (const float*)d_in[6];

  // Working state in d_ws:
  //   [0, 64MB)        : z packed f16 (re,im) per pixel, u32 [4,64,256,256]
  //   [64MB, 64MB+1MB) : xhat bf16 ushort2
  u32*     zws = (u32*)d_ws;
  ushort2* xws = (ushort2*)((char*)d_ws + (size_t)67108864);

  // Scratch in d_out head (all dead before emit):
  //   [0, 8MB)     : convT residual fp32 partials (4 splits x 4 b x HW float2)
  //   [8MB, 16MB)  : convT final fp32 partials
  //   [16MB,+32)   : mean ; [16MB+64, +2112) : part
  //   [17MB,+74KB) : wA packed f16 weights ; [18MB,+74KB): wB
  //   [19MB, +1MB) : rq packed f16 residual
  char* ob = (char*)d_out;
  float2* rpart = (float2*)ob;
  float2* xpart = (float2*)(ob + 8388608);
  float2* mean  = (float2*)(ob + 16777216);
  float2* part  = (float2*)(ob + 16777280);
  uint2*  wA    = (uint2*)(ob + 17825792);
  uint2*  wB    = (uint2*)(ob + 18874368);
  u32*    rq    = (u32*)(ob + 19922944);

  wprep_kernel<<<(NTAP + 255)/256, 256, 0, stream>>>(Awre, Awim, Bwre, Bwim, wA, wB);
  mean_stage1<<<256, 256, 0, stream>>>(yre, yim, part);
  mean_stage2<<<1, 256, 0, stream>>>(part, mean);

  dim3 gridA(NB * (Hh/ATY) * (Ww/ATX) * NSPL);   // 2048 blocks (A-convs)
  dim3 gridT(NB * (Hh/PT) * (Ww/PT) * NSPL);     // 1024 blocks (convT)
  conv_first_kernel<<<gridA, 256, 0, stream>>>(yre, yim, mean, wA, t, zws);
  for (int k = 1; k < 3; ++k) {
    convT_part_kernel<<<gridT, 256, 0, stream>>>(zws, wB, k, rpart);
    rfold_kernel<<<NX/256, 256, 0, stream>>>(rpart, yre, yim, mean, rq);
    conv_update_kernel<<<gridA, 256, 0, stream>>>(rq, wA, t, k, zws);
  }
  convT_part_kernel<<<gridT, 256, 0, stream>>>(zws, wB, 0, xpart);
  xreduce_kernel<<<NX/256, 256, 0, stream>>>(xpart, mean, xws);

  size_t total = (size_t)NX + NZQ;
  emit_kernel<<<(unsigned)(total/256), 256, 0, stream>>>(xws, zws, (u16*)d_out);
}

// Round 29
// 450.752 us; speedup vs baseline: 1.4981x; 1.0031x over previous
//
#include <hip/hip_runtime.h>

#define Hh 256
#define Ww 256
#define NB 4
#define NM 64
#define KP 7
#define HW (Hh*Ww)
#define NX (NB*HW)                 // 262144 xhat pixels
#define NZQ ((size_t)NB*NM*HW)     // 16777216 z pixels
// convT tiles
#define PT 32
#define TW2 38
#define LDS2T 42                   // uint4 row stride: 168 dwords % 32 = 8 -> bank rotation
#define NST 6
// A-conv tiles: 16 rows x 32 cols, 2 px/thread
#define ATY 16
#define ATX 32
#define ATWY 22
#define ATWX 38
#define ALDS 40
#define NTAP (3*NM*49)             // 9408 weight taps per array
#define NSPL 4                     // channel splits (16 ch per block)

typedef unsigned short u16;
typedef unsigned int u32;

__device__ __forceinline__ float bf2f(u16 u) {
  union { u32 i; float f; } c; c.i = ((u32)u) << 16; return c.f;
}
__device__ __forceinline__ u16 f2bf(float f) {
  union { float f; u32 i; } c; c.f = f;
  return (u16)((c.i + 0x7FFFu + ((c.i >> 16) & 1u)) >> 16);   // RNE
}
__device__ __forceinline__ ushort2 packbf(float x, float y) {
  return make_ushort2(f2bf(x), f2bf(y));
}

// ---- f16 pair helpers (packed complex value in one dword: low=re, high=im) ----
__device__ __forceinline__ u32 packh(float x, float y) {
  union { u32 u; _Float16 h[2]; } c;
  c.h[0] = (_Float16)x; c.h[1] = (_Float16)y;
  return c.u;
}
__device__ __forceinline__ float2 unpackh(u32 v) {
  union { u32 u; _Float16 h[2]; } c; c.u = v;
  return make_float2((float)c.h[0], (float)c.h[1]);
}
__device__ __forceinline__ u16 h2bf(u16 hraw) {
  union { u16 u; _Float16 h; } c; c.u = hraw;
  return f2bf((float)c.h);
}

#if __has_builtin(__builtin_amdgcn_fdot2)
typedef _Float16 hf2 __attribute__((ext_vector_type(2)));
__device__ __forceinline__ void cmac2(float& ar, float& ai, u32 v, u32 wre, u32 wim) {
  union { u32 u; hf2 h; } a, b, c;
  a.u = v; b.u = wre; c.u = wim;
  ar = __builtin_amdgcn_fdot2(a.h, b.h, ar, false);
  ai = __builtin_amdgcn_fdot2(a.h, c.h, ai, false);
}
#else
__device__ __forceinline__ void cmac2(float& ar, float& ai, u32 v, u32 wre, u32 wim) {
  float2 a = unpackh(v), b = unpackh(wre), c = unpackh(wim);
  ar = fmaf(a.x, b.x, ar); ar = fmaf(a.y, b.y, ar);
  ai = fmaf(a.x, c.x, ai); ai = fmaf(a.y, c.y, ai);
}
#endif

// soft-threshold factor: max(1 - t*rsqrt(s), 0), s = re^2+im^2.
__device__ __forceinline__ float stfac(float s, float t) {
  return fmaxf(1.f - t*rsqrtf(s), 0.f);
}

// ---------------- weight prep: pack (wr,-wi),(wi,wr) as f16 pairs ----------------
__global__ __launch_bounds__(256) void wprep_kernel(
    const float* __restrict__ Awre, const float* __restrict__ Awim,
    const float* __restrict__ Bwre, const float* __restrict__ Bwim,
    uint2* __restrict__ wA, uint2* __restrict__ wB) {
  int i = blockIdx.x*256 + threadIdx.x;
  if (i < NTAP) {
    float wr = Awre[i], wi = Awim[i];
    wA[i] = make_uint2(packh(wr, -wi), packh(wi, wr));
    wr = Bwre[i]; wi = Bwim[i];
    wB[i] = make_uint2(packh(wr, -wi), packh(wi, wr));
  }
}

// ---------------- mean over (C,H,W) per batch, complex ----------------
__global__ __launch_bounds__(256) void mean_stage1(
    const float* __restrict__ yre, const float* __restrict__ yim,
    float2* __restrict__ part) {
  int blk = blockIdx.x;           // 256 blocks: 64 per batch
  int b = blk >> 6, chunk = blk & 63;
  int tid = threadIdx.x;
  int base = b*HW + chunk*1024;
  float sr = 0.f, si = 0.f;
  #pragma unroll
  for (int j = 0; j < 4; ++j) {
    sr += yre[base + tid + j*256];
    si += yim[base + tid + j*256];
  }
  #pragma unroll
  for (int off = 32; off > 0; off >>= 1) {
    sr += __shfl_down(sr, off);
    si += __shfl_down(si, off);
  }
  __shared__ float2 red[4];
  if ((tid & 63) == 0) red[tid >> 6] = make_float2(sr, si);
  __syncthreads();
  if (tid == 0) {
    float2 a = red[0], b2 = red[1], c = red[2], d = red[3];
    part[blk] = make_float2(a.x + b2.x + c.x + d.x, a.y + b2.y + c.y + d.y);
  }
}

__global__ __launch_bounds__(256) void mean_stage2(
    const float2* __restrict__ part, float2* __restrict__ mean) {
  int tid = threadIdx.x;
  int b = tid >> 6, lane = tid & 63;
  float2 v = part[b*64 + lane];
  float sr = v.x, si = v.y;
  #pragma unroll
  for (int off = 32; off > 0; off >>= 1) {
    sr += __shfl_down(sr, off);
    si += __shfl_down(si, off);
  }
  if (lane == 0) mean[b] = make_float2(sr / (float)HW, si / (float)HW);
}

// ---------------- z0 = ST(conv(yp, A0), t[0,0]) — 16ch/block, 8ch/group, 2px ----------------
__global__ __launch_bounds__(256) void conv_first_kernel(
    const float* __restrict__ yre, const float* __restrict__ yim,
    const float2* __restrict__ mean,
    const uint2* __restrict__ wA,
    const float* __restrict__ t, u32* __restrict__ z) {
  int tid = threadIdx.x;
  int blk = blockIdx.x;                 // 2048 = ms + 4*(txi + 8*(tyi + 16*b))
  int ms  = blk & 3;
  int txi = (blk >> 2) & 7, tyi = (blk >> 5) & 15, b = (blk >> 9) & 3;
  int ty0 = tyi*ATY, tx0 = txi*ATX;
  int thy = tid >> 4, thx = tid & 15;

  __shared__ u32 tile[ATWY][ALDS];
  float2 mb = mean[b];
  const float* re = yre + b*HW;
  const float* im = yim + b*HW;
  for (int i = tid; i < ATWY*ATWX; i += 256) {
    int rr = i / ATWX, cc = i - rr*ATWX;
    int gy = ty0 - 3 + rr, gx = tx0 - 3 + cc;
    u32 v = 0;
    if ((unsigned)gy < Hh && (unsigned)gx < Ww) {
      int o = gy*Ww + gx;
      v = packh(re[o] - mb.x, im[o] - mb.y);
    }
    tile[rr][cc] = v;
  }
  __syncthreads();

  u32* zb = z + ((size_t)b*NM << 16);
  int m0 = ms*16;
  #pragma unroll 1
  for (int mm = 0; mm < 16; mm += 8) {
    int m = m0 + mm;
    const uint2* w0p = wA + m*49;       // k = 0
    float ar[8][2], ai[8][2];
    #pragma unroll
    for (int c = 0; c < 8; ++c) {
      ar[c][0] = 0.f; ar[c][1] = 0.f; ai[c][0] = 0.f; ai[c][1] = 0.f;
    }
    #pragma unroll
    for (int ky = 0; ky < KP; ++ky) {
      #pragma unroll
      for (int kx = 0; kx < KP; ++kx) {
        int wo = ky*KP + kx;
        u32 v0 = tile[thy + ky][thx + kx];
        u32 v1 = tile[thy + ky][thx + 16 + kx];
        #pragma unroll
        for (int c = 0; c < 8; ++c) {
          uint2 w = w0p[c*49 + wo];
          cmac2(ar[c][0], ai[c][0], v0, w.x, w.y);
          cmac2(ar[c][1], ai[c][1], v1, w.x, w.y);
        }
      }
    }
    #pragma unroll
    for (int c = 0; c < 8; ++c) {
      float tc = t[m + c];              // t[0,0,m+c]
      #pragma unroll
      for (int p = 0; p < 2; ++p) {
        size_t o = (size_t)(ty0 + thy)*Ww + tx0 + thx + p*16;
        float s = ar[c][p]*ar[c][p] + ai[c][p]*ai[c][p];
        float f = stfac(s, tc);
        zb[((size_t)(m + c) << 16) + o] = packh(ar[c][p]*f, ai[c][p]*f);
      }
    }
  }
}

// ---------------- partial convT over 16 ch (4ch packed uint4, single-buffer) ----------------
__global__ __launch_bounds__(256) void convT_part_kernel(
    const u32* __restrict__ z,
    const uint2* __restrict__ wB,
    int k, float2* __restrict__ rpart) {
  int tid = threadIdx.x;
  int blk = blockIdx.x;                 // 1024 = s + 4*(txi + 8*(tyi + 8*b))
  int s   = blk & 3;
  int txi = (blk >> 2) & 7, tyi = (blk >> 5) & 7, b = (blk >> 8) & 3;
  int ty0 = tyi*PT, tx0 = txi*PT;
  int thy = tid >> 4, thx = tid & 15;

  __shared__ uint4 tile[TW2][LDS2T];    // stride 42 -> rows rotate 8 banks

  int srr[NST], scc[NST], soff[NST];
  bool sok[NST], sin[NST];
  #pragma unroll
  for (int j = 0; j < NST; ++j) {
    int i = tid + j*256;
    sin[j] = i < TW2*TW2;
    int rr = sin[j] ? i / TW2 : 0;
    int cc = sin[j] ? i - rr*TW2 : 0;
    int gy = ty0 - 3 + rr, gx = tx0 - 3 + cc;
    sok[j] = sin[j] && (unsigned)gy < Hh && (unsigned)gx < Ww;
    srr[j] = rr; scc[j] = cc;
    soff[j] = sok[j] ? gy*Ww + gx : 0;
  }

  const u32* zb = z + ((size_t)b*NM << 16);
  int m0 = s*16;

  float ar[4] = {0.f,0.f,0.f,0.f}, ai[4] = {0.f,0.f,0.f,0.f};
  #pragma unroll 1
  for (int q = 0; q < 4; ++q) {         // 4 channel quads
    int m = m0 + 4*q;
    if (q) __syncthreads();             // protect previous iteration's reads
    {
      const u32* z0 = zb + ((size_t)m << 16);
      const u32* z1 = zb + ((size_t)(m + 1) << 16);
      const u32* z2 = zb + ((size_t)(m + 2) << 16);
      const u32* z3 = zb + ((size_t)(m + 3) << 16);
      #pragma unroll
      for (int j = 0; j < NST; ++j)
        if (sin[j]) tile[srr[j]][scc[j]] = make_uint4(
          sok[j] ? z0[soff[j]] : 0u, sok[j] ? z1[soff[j]] : 0u,
          sok[j] ? z2[soff[j]] : 0u, sok[j] ? z3[soff[j]] : 0u);
    }
    __syncthreads();

    const uint2* w0p = wB + (k*NM + m)*49;
    #pragma unroll
    for (int ky = 0; ky < KP; ++ky) {
      #pragma unroll
      for (int kx = 0; kx < KP; ++kx) {
        int wo = ky*KP + kx;
        uint2 wa = w0p[wo], wb = w0p[49 + wo], wc = w0p[98 + wo], wd = w0p[147 + wo];
        #pragma unroll
        for (int dy = 0; dy < 2; ++dy) {
          #pragma unroll
          for (int dx = 0; dx < 2; ++dx) {
            uint4 v = tile[thy + dy*16 + 6 - ky][thx + dx*16 + 6 - kx];
            int p = dy*2 + dx;
            cmac2(ar[p], ai[p], v.x, wa.x, wa.y);
            cmac2(ar[p], ai[p], v.y, wb.x, wb.y);
            cmac2(ar[p], ai[p], v.z, wc.x, wc.y);
            cmac2(ar[p], ai[p], v.w, wd.x, wd.y);
          }
        }
      }
    }
  }

  float2* rp = rpart + (size_t)s*NB*HW + (size_t)b*HW;
  #pragma unroll
  for (int dy = 0; dy < 2; ++dy) {
    #pragma unroll
    for (int dx = 0; dx < 2; ++dx) {
      int p = dy*2 + dx;
      int o = (ty0 + thy + dy*16)*Ww + tx0 + thx + dx*16;
      rp[o] = make_float2(ar[p], ai[p]);
    }
  }
}

// ---------------- rfold: rq = packh(Σ4 rpart − (y − mean)) ----------------
__global__ __launch_bounds__(256) void rfold_kernel(
    const float2* __restrict__ rpart,
    const float* __restrict__ yre, const float* __restrict__ yim,
    const float2* __restrict__ mean, u32* __restrict__ rq) {
  int p = blockIdx.x*256 + threadIdx.x;   // 0..NX (p = b*HW + px)
  int b = p >> 16;
  float2 mb = mean[b];
  float2 p0 = rpart[p];
  float2 p1 = rpart[(size_t)NB*HW + p];
  float2 p2 = rpart[(size_t)2*NB*HW + p];
  float2 p3 = rpart[(size_t)3*NB*HW + p];
  rq[p] = packh(p0.x + p1.x + p2.x + p3.x - (yre[p] - mb.x),
                p0.y + p1.y + p2.y + p3.y - (yim[p] - mb.y));
}

// ---------------- z = ST(z - conv(rq, A[k]), t[k,0]) — 16ch/block, 8ch/group, 2px ----------------
__global__ __launch_bounds__(256) void conv_update_kernel(
    const u32* __restrict__ rq,
    const uint2* __restrict__ wA,
    const float* __restrict__ t, int k, u32* __restrict__ z) {
  int tid = threadIdx.x;
  int blk = blockIdx.x;                 // 2048 = ms + 4*(txi + 8*(tyi + 16*b))
  int ms  = blk & 3;
  int txi = (blk >> 2) & 7, tyi = (blk >> 5) & 15, b = (blk >> 9) & 3;
  int ty0 = tyi*ATY, tx0 = txi*ATX;
  int thy = tid >> 4, thx = tid & 15;

  __shared__ u32 tile[ATWY][ALDS];
  const u32* rb = rq + b*HW;
  for (int i = tid; i < ATWY*ATWX; i += 256) {
    int rr = i / ATWX, cc = i - rr*ATWX;
    int gy = ty0 - 3 + rr, gx = tx0 - 3 + cc;
    u32 v = 0;
    if ((unsigned)gy < Hh && (unsigned)gx < Ww) v = rb[gy*Ww + gx];
    tile[rr][cc] = v;
  }
  __syncthreads();

  const float* tw = t + k*2*NM;         // t[k,0,:]
  u32* zb = z + ((size_t)b*NM << 16);
  int m0 = ms*16;
  #pragma unroll 1
  for (int mm = 0; mm < 16; mm += 8) {
    int m = m0 + mm;
    const uint2* w0p = wA + (k*NM + m)*49;
    float ar[8][2], ai[8][2];
    #pragma unroll
    for (int c = 0; c < 8; ++c) {
      ar[c][0] = 0.f; ar[c][1] = 0.f; ai[c][0] = 0.f; ai[c][1] = 0.f;
    }
    #pragma unroll
    for (int ky = 0; ky < KP; ++ky) {
      #pragma unroll
      for (int kx = 0; kx < KP; ++kx) {
        int wo = ky*KP + kx;
        u32 v0 = tile[thy + ky][thx + kx];
        u32 v1 = tile[thy + ky][thx + 16 + kx];
        #pragma unroll
        for (int c = 0; c < 8; ++c) {
          uint2 w = w0p[c*49 + wo];
          cmac2(ar[c][0], ai[c][0], v0, w.x, w.y);
          cmac2(ar[c][1], ai[c][1], v1, w.x, w.y);
        }
      }
    }
    #pragma unroll
    for (int c = 0; c < 8; ++c) {
      float tc = tw[m + c];
      #pragma unroll
      for (int p = 0; p < 2; ++p) {
        size_t o = (size_t)(ty0 + thy)*Ww + tx0 + thx + p*16;
        size_t q0 = ((size_t)(m + c) << 16) + o;
        float2 z0 = unpackh(zb[q0]);
        float zr0 = z0.x - ar[c][p], zi0 = z0.y - ai[c][p];
        float s = zr0*zr0 + zi0*zi0;
        float f = stfac(s, tc);
        zb[q0] = packh(zr0*f, zi0*f);
      }
    }
  }
}

// ---------------- xhat partial reduce: xws = bf16(Σx + mean) ----------------
__global__ __launch_bounds__(256) void xreduce_kernel(
    const float2* __restrict__ xpart,
    const float2* __restrict__ mean, ushort2* __restrict__ xws) {
  int p = blockIdx.x*256 + threadIdx.x;   // 0..NX
  int b = p >> 16;
  float2 mb = mean[b];
  float2 a0 = xpart[p];
  float2 a1 = xpart[(size_t)NB*HW + p];
  float2 a2 = xpart[(size_t)2*NB*HW + p];
  float2 a3 = xpart[(size_t)3*NB*HW + p];
  xws[p] = packbf(a0.x + a1.x + a2.x + a3.x + mb.x,
                  a0.y + a1.y + a2.y + a3.y + mb.y);
}

// ---------------- emit: shifted (+1 element) copy into d_out; z f16->bf16 ----------------
__global__ __launch_bounds__(256) void emit_kernel(
    const ushort2* __restrict__ xws, const u32* __restrict__ zws,
    u16* __restrict__ out16) {
  size_t idx = (size_t)blockIdx.x*256 + threadIdx.x;
  ushort2* out2 = (ushort2*)out16;
  if (idx < (size_t)NX) {
    int p = (int)idx;
    ushort2 xp = xws[p];
    u16 nxt = (p + 1 < NX) ? xws[p + 1].x
                           : h2bf((u16)(zws[0] & 0xffffu));
    out2[p + 1] = make_ushort2(xp.y, nxt);
    if (p == 0) out16[1] = xp.x;
  } else {
    size_t q = idx - (size_t)NX;
    u32 zq = zws[q];
    u16 zim = h2bf((u16)(zq >> 16));
    if (q + 1 < NZQ) {
      u16 zre_next = h2bf((u16)(zws[q + 1] & 0xffffu));
      out2[(size_t)262145 + q] = make_ushort2(zim, zre_next);
    } else {
      out16[(size_t)2*NX + 2*NZQ] = zim;
    }
  }
}

extern "C" void kernel_launch(void* const* d_in, const int* in_sizes, int n_in,
                              void* d_out, int out_size, void* d_ws, size_t ws_size,
                              hipStream_t stream) {
  const float* yre  = (const float*)d_in[0];
  const float* yim  = (const float*)d_in[1];
  const float* Awre = (const float*)d_in[2];
  const float* Awim = (const float*)d_in[3];
  const float* Bwre = (const float*)d_in[4];
  const float* Bwim = (const float*)d_in[5];
  const float* t    = (const float*)d_in[6];

  // Working state in d_ws:
  //   [0, 64MB)        : z packed f16 (re,im) per pixel, u32 [4,64,256,256]
  //   [64MB, 64MB+1MB) : xhat bf16 ushort2
  u32*     zws = (u32*)d_ws;
  ushort2* xws = (ushort2*)((char*)d_ws + (size_t)67108864);

  // Scratch in d_out head (all dead before emit):
  //   [0, 8MB)     : convT residual fp32 partials (4 splits x 4 b x HW float2)
  //   [8MB, 16MB)  : convT final fp32 partials
  //   [16MB,+32)   : mean ; [16MB+64, +2112) : part
  //   [17MB,+74KB) : wA packed f16 weights ; [18MB,+74KB): wB
  //   [19MB, +1MB) : rq packed f16 residual
  char* ob = (char*)d_out;
  float2* rpart = (float2*)ob;
  float2* xpart = (float2*)(ob + 8388608);
  float2* mean  = (float2*)(ob + 16777216);
  float2* part  = (float2*)(ob + 16777280);
  uint2*  wA    = (uint2*)(ob + 17825792);
  uint2*  wB    = (uint2*)(ob + 18874368);
  u32*    rq    = (u32*)(ob + 19922944);

  wprep_kernel<<<(NTAP + 255)/256, 256, 0, stream>>>(Awre, Awim, Bwre, Bwim, wA, wB);
  mean_stage1<<<256, 256, 0, stream>>>(yre, yim, part);
  mean_stage2<<<1, 256, 0, stream>>>(part, mean);

  dim3 gridA(NB * (Hh/ATY) * (Ww/ATX) * NSPL);   // 2048 blocks (A-convs)
  dim3 gridT(NB * (Hh/PT) * (Ww/PT) * NSPL);     // 1024 blocks (convT)
  conv_first_kernel<<<gridA, 256, 0, stream>>>(yre, yim, mean, wA, t, zws);
  for (int k = 1; k < 3; ++k) {
    convT_part_kernel<<<gridT, 256, 0, stream>>>(zws, wB, k, rpart);
    rfold_kernel<<<NX/256, 256, 0, stream>>>(rpart, yre, yim, mean, rq);
    conv_update_kernel<<<gridA, 256, 0, stream>>>(rq, wA, t, k, zws);
  }
  convT_part_kernel<<<gridT, 256, 0, stream>>>(zws, wB, 0, xpart);
  xreduce_kernel<<<NX/256, 256, 0, stream>>>(xpart, mean, xws);

  size_t total = (size_t)NX + NZQ;
  emit_kernel<<<(unsigned)(total/256), 256, 0, stream>>>(xws, zws, (u16*)d_out);
}